// Round 10
// baseline (130.455 us; speedup 1.0000x reference)
//
#include <hip/hip_runtime.h>
#include <cstdint>

// B=4, S=512, D=512, H=8, TM=20, DH=64
// out layout: out[1048576] | attn[8388608] | reg[1] | T_i[2048]  (all float)

typedef __attribute__((ext_vector_type(8))) _Float16 f16x8;
typedef __attribute__((ext_vector_type(4))) float f32x4;

__device__ __forceinline__ float sep_mad(float a, float b, float c) {
    // separate mul+add rounding (matches numpy), blocks FMA contraction:
    // spike threshold is discontinuous.
    float t = a * b;
    asm volatile("" : "+v"(t));
    return t + c;
}

union HU4 { _Float16 h[4]; ushort4 u; };
union HU8 { _Float16 h[8]; uint4 u; };

__device__ __forceinline__ void split4(float4 v, HU4& hi, HU4& lo) {
    hi.h[0] = (_Float16)v.x; lo.h[0] = (_Float16)(v.x - (float)hi.h[0]);
    hi.h[1] = (_Float16)v.y; lo.h[1] = (_Float16)(v.y - (float)hi.h[1]);
    hi.h[2] = (_Float16)v.z; lo.h[2] = (_Float16)(v.z - (float)hi.h[2]);
    hi.h[3] = (_Float16)v.w; lo.h[3] = (_Float16)(v.w - (float)hi.h[3]);
}

// ---------------- Kernel 1: unified fp16x3 MFMA GEMM with fused fp32->hi/lo split ----------------
// Y[2048][1664] = x @ [Wq|Wk|Wv|gw1|cw1|pad]^T, all staged fp32->fp16 hi/lo in-kernel.
// BM=BN=64, BK=32, 256 thr = 4 waves wave-tile 32x32, 3 hi/lo MFMA products.
__global__ __launch_bounds__(256) void k_gemm3(
    const float* __restrict__ X,
    const float* __restrict__ Wq, const float* __restrict__ Wk,
    const float* __restrict__ Wv, const float* __restrict__ gw1,
    const float* __restrict__ cw1,
    float* __restrict__ Y)
{
    __shared__ _Float16 AsH[4][64][8];
    __shared__ _Float16 BsH[4][64][8];
    __shared__ _Float16 AsL[4][64][8];
    __shared__ _Float16 BsL[4][64][8];

    const int bn = blockIdx.x * 64, bm = blockIdx.y * 64;
    const int tid = threadIdx.x, w = tid >> 6, l = tid & 63;
    const int mB = (w & 1) * 32, nB = (w >> 1) * 32;
    const int sr = tid >> 2, sk = tid & 3;
    const int fr = l & 15, fk = l >> 4;

    // per-thread source rows (constant across K-steps)
    const float* asrc = X + (bm + sr) * 512;
    const int brow = bn + sr;                 // concat row in [Wq|Wk|Wv|gw1|cw1|pad]
    const float* bsrc;
    bool bvalid = true;
    if      (brow < 512)  bsrc = Wq  + brow * 512;
    else if (brow < 1024) bsrc = Wk  + (brow - 512) * 512;
    else if (brow < 1536) bsrc = Wv  + (brow - 1024) * 512;
    else if (brow < 1600) bsrc = gw1 + (brow - 1536) * 512;
    else if (brow < 1632) bsrc = cw1 + (brow - 1600) * 512;
    else { bsrc = Wq; bvalid = false; }       // pad rows -> zeros

    f32x4 acc[2][2] = {};
    const float4 z4{0.f, 0.f, 0.f, 0.f};

    float4 pa0 = *(const float4*)(asrc + sk * 8);
    float4 pa1 = *(const float4*)(asrc + sk * 8 + 4);
    float4 pb0 = bvalid ? *(const float4*)(bsrc + sk * 8)     : z4;
    float4 pb1 = bvalid ? *(const float4*)(bsrc + sk * 8 + 4) : z4;

    for (int k0 = 0; k0 < 512; k0 += 32) {
        __syncthreads();
        {
            HU4 h0, l0, h1, l1;
            split4(pa0, h0, l0); split4(pa1, h1, l1);
            *(ushort4*)&AsH[sk][sr][0] = h0.u; *(ushort4*)&AsH[sk][sr][4] = h1.u;
            *(ushort4*)&AsL[sk][sr][0] = l0.u; *(ushort4*)&AsL[sk][sr][4] = l1.u;
            split4(pb0, h0, l0); split4(pb1, h1, l1);
            *(ushort4*)&BsH[sk][sr][0] = h0.u; *(ushort4*)&BsH[sk][sr][4] = h1.u;
            *(ushort4*)&BsL[sk][sr][0] = l0.u; *(ushort4*)&BsL[sk][sr][4] = l1.u;
        }
        __syncthreads();
        const int kn = (k0 + 32) & 511;   // wraps harmlessly on last iter
        pa0 = *(const float4*)(asrc + kn + sk * 8);
        pa1 = *(const float4*)(asrc + kn + sk * 8 + 4);
        if (bvalid) {
            pb0 = *(const float4*)(bsrc + kn + sk * 8);
            pb1 = *(const float4*)(bsrc + kn + sk * 8 + 4);
        }

        f16x8 ah[2], al[2];
#pragma unroll
        for (int mt = 0; mt < 2; mt++) {
            ah[mt] = *(const f16x8*)&AsH[fk][mB + mt * 16 + fr][0];
            al[mt] = *(const f16x8*)&AsL[fk][mB + mt * 16 + fr][0];
        }
#pragma unroll
        for (int nt = 0; nt < 2; nt++) {
            f16x8 bh = *(const f16x8*)&BsH[fk][nB + nt * 16 + fr][0];
            f16x8 bl = *(const f16x8*)&BsL[fk][nB + nt * 16 + fr][0];
#pragma unroll
            for (int mt = 0; mt < 2; mt++) {
                acc[mt][nt] = __builtin_amdgcn_mfma_f32_16x16x32_f16(ah[mt], bh, acc[mt][nt], 0, 0, 0);
                acc[mt][nt] = __builtin_amdgcn_mfma_f32_16x16x32_f16(ah[mt], bl, acc[mt][nt], 0, 0, 0);
                acc[mt][nt] = __builtin_amdgcn_mfma_f32_16x16x32_f16(al[mt], bh, acc[mt][nt], 0, 0, 0);
            }
        }
    }

#pragma unroll
    for (int mt = 0; mt < 2; mt++) {
#pragma unroll
        for (int nt = 0; nt < 2; nt++) {
            const int j = bn + nB + nt * 16 + fr;
#pragma unroll
            for (int rr = 0; rr < 4; rr++) {
                const int i = bm + mB + mt * 16 + fk * 4 + rr;
                Y[i * 1664 + j] = acc[mt][nt][rr];
            }
        }
    }
}

// ---------------- Kernel 2: LIF + fused gate-layers-2/3 + ballot bit-pack + v_mean transpose ----
// grid (32, 32): blockIdx.y = bh, blockIdx.x = 16-token s-block. 256 thr = 4 waves.
// Gate layers 2/3 recomputed per block (8x redundant across h, bit-identical).
__global__ __launch_bounds__(256) void k_lif(
    const float* __restrict__ qkvh1,         // [2048][1664]  (q|k|v|h1raw per row)
    const float* __restrict__ gb1, const float* __restrict__ cb1,
    const float* __restrict__ gw2, const float* __restrict__ gb2,
    const float* __restrict__ gw3, const float* __restrict__ gb3,
    const float* __restrict__ cw2, const float* __restrict__ cb2,
    const float* __restrict__ pAlpha, const float* __restrict__ pBeta,
    unsigned long long* __restrict__ qbits,  // [(bh*20)+t]*512 + s
    unsigned long long* __restrict__ kbits,
    _Float16* __restrict__ vmT,              // [bh][d][s]
    int* __restrict__ Ti, float* __restrict__ ti_out)
{
    __shared__ _Float16 cnts[64][18];        // [d][s_local], pad 18 (<=2-way, free)
    __shared__ float h1s[16][100];
    __shared__ float h2s[16][36];
    __shared__ int tis[16];
    const int tid = threadIdx.x;
    const int wid = tid >> 6, lane = tid & 63;
    const int bh = blockIdx.y, s0 = blockIdx.x * 16;
    const int b = bh >> 3, h = bh & 7;
    const float alpha = pAlpha[0], beta = pBeta[0];

    // ---- fused gate layers 2+3 -> Ti for these 16 tokens (matches k_gates2 math exactly) ----
    for (int i = tid; i < 1536; i += 256) {
        const int r = i / 96, c = i % 96;
        const float v = qkvh1[(long)(b * 512 + s0 + r) * 1664 + 1536 + c]
                        + (c < 64 ? gb1[c] : cb1[c - 64]);
        h1s[r][c] = fmaxf(v, 0.f);
    }
    __syncthreads();
#pragma unroll
    for (int ii = 0; ii < 2; ii++) {
        const int idx = tid + ii * 256;      // 0..511 = (tok, o2)
        const int tok = idx >> 5, o2 = idx & 31;
        const float* w2 = gw2 + o2 * 64;
        float a = gb2[o2];
        for (int k = 0; k < 64; k++) a = fmaf(w2[k], h1s[tok][k], a);
        h2s[tok][o2] = fmaxf(a, 0.f);
    }
    __syncthreads();
    if (tid < 16) {
        const int tok = tid;
        float gg = gb3[0], cc = cb2[0];
        for (int k = 0; k < 32; k++) {
            gg = fmaf(gw3[k], h2s[tok][k], gg);
            cc = fmaf(cw2[k], h1s[tok][64 + k], cc);
        }
        float g = 1.f / (1.f + expf(-gg));
        float c = 1.f / (1.f + expf(-cc));
        float p1 = 0.7f * g, p2 = 0.3f * c;
        asm volatile("" : "+v"(p1), "+v"(p2));
        float comb = p1 + p2;
        float tf = ceilf(comb * 20.0f);
        tf = fminf(fmaxf(tf, 1.f), 20.f);
        tis[tok] = (int)tf;
        Ti[b * 512 + s0 + tok] = (int)tf;    // redundant x8 across h, identical values
        ti_out[b * 512 + s0 + tok] = tf;
    }
    __syncthreads();

    // ---- LIF: 4 rounds of 4 tokens ----
    const float* qrow0 = qkvh1 + (long)(b * 512 + s0 + wid) * 1664 + h * 64 + lane;
    float cq = qrow0[0], ck = qrow0[512], cv = qrow0[1024];

    for (int r = 0; r < 4; r++) {
        const int tl = r * 4 + wid;          // token_local 0..15
        const int s = s0 + tl;
        float nq = 0.f, nk = 0.f, nv = 0.f;
        if (r < 3) {
            const float* qr = qkvh1 + (long)(b * 512 + s + 4) * 1664 + h * 64 + lane;
            nq = qr[0]; nk = qr[512]; nv = qr[1024];
        }
        const int T = tis[tl];
        float iq = 0.f, vq = 0.f, ik = 0.f, vk = 0.f, iv = 0.f, vv = 0.f;
        int cnt = 0;
        const int base = (bh * 20) * 512 + s;
#pragma unroll
        for (int t = 0; t < 20; t++) {
            iq = sep_mad(alpha, iq, cq); vq = sep_mad(beta, vq, iq);
            bool sq = vq >= 1.0f; vq = sq ? 0.f : vq;
            ik = sep_mad(alpha, ik, ck); vk = sep_mad(beta, vk, ik);
            bool sk = vk >= 1.0f; vk = sk ? 0.f : vk;
            iv = sep_mad(alpha, iv, cv); vv = sep_mad(beta, vv, iv);
            bool sv = vv >= 1.0f; vv = sv ? 0.f : vv;
            bool act = t < T;
            unsigned long long mq = __ballot(sq && act);
            unsigned long long mk = __ballot(sk && act);
            if (lane == 0) {
                qbits[base + t * 512] = mq;
                kbits[base + t * 512] = mk;
            }
            cnt += (sv && act) ? 1 : 0;
        }
        cnts[lane][tl] = (_Float16)((float)cnt / 20.0f);
        cq = nq; ck = nk; cv = nv;
    }
    __syncthreads();
    // write vmT[bh][d][s0..s0+15]: thread (d = tid>>2, q = tid&3) -> 4 fp16 = 8B
    const int d = tid >> 2, q = tid & 3;
    HU4 o;
#pragma unroll
    for (int i = 0; i < 4; i++) o.h[i] = cnts[d][q * 4 + i];
    *(ushort4*)(vmT + (bh * 64 + d) * 512 + s0 + q * 4) = o.u;
}

// ---------------- Kernel 3: popcount scores + softmax -> attn (+fused reg) ----------------
__global__ __launch_bounds__(256) void k_scores(
    const unsigned long long* __restrict__ qbits,
    const unsigned long long* __restrict__ kbits,
    float* __restrict__ attn,
    const int* __restrict__ Ti, float* __restrict__ regp)
{
    const int bh = blockIdx.x >> 5;            // 0..31
    const int i0 = (blockIdx.x & 31) * 16;
    const int base = bh * 20 * 512;
    __shared__ unsigned long long qs[20][16];
    __shared__ float sc[16][512];
    const int tid = threadIdx.x;
    for (int idx = tid; idx < 320; idx += 256) {
        int t = idx >> 4, r = idx & 15;
        qs[t][r] = qbits[base + t * 512 + i0 + r];
    }
    int Tmax = 0;
    const int tb = (bh >> 3) * 512 + i0;
#pragma unroll
    for (int r = 0; r < 16; r++) Tmax = max(Tmax, Ti[tb + r]);
    __syncthreads();

    {
        // thread handles adjacent j-pair (2*tid, 2*tid+1): 16B kbits loads
        const unsigned long long* kbp = kbits + base + 2 * tid;
        int acc0[16] = {}, acc1[16] = {};
        for (int tc = 0; tc < 4; tc++) {
            if (tc * 5 >= Tmax) break;
            unsigned long long kv0[5], kv1[5];
#pragma unroll
            for (int t = 0; t < 5; t++) {
                ulonglong2 kk = *(const ulonglong2*)(kbp + (tc * 5 + t) * 512);
                kv0[t] = kk.x; kv1[t] = kk.y;
            }
#pragma unroll
            for (int r = 0; r < 16; r++) {
#pragma unroll
                for (int t = 0; t < 5; t++) {
                    unsigned long long qv = qs[tc * 5 + t][r];
                    acc0[r] += __popcll(qv & kv0[t]);
                    acc1[r] += __popcll(qv & kv1[t]);
                }
            }
        }
#pragma unroll
        for (int r = 0; r < 16; r++) {
            sc[r][2 * tid]     = (float)acc0[r] * 0.125f;
            sc[r][2 * tid + 1] = (float)acc1[r] * 0.125f;
        }
    }
    __syncthreads();

    const int wid = tid >> 6, lane = tid & 63;
#pragma unroll
    for (int rr = 0; rr < 4; rr++) {
        const int r = wid * 4 + rr;
        float vals[8];
        float m = -1e30f;
#pragma unroll
        for (int k = 0; k < 8; k++) { vals[k] = sc[r][lane + 64 * k]; m = fmaxf(m, vals[k]); }
#pragma unroll
        for (int off = 32; off; off >>= 1) m = fmaxf(m, __shfl_xor(m, off));
        float sum = 0.f;
#pragma unroll
        for (int k = 0; k < 8; k++) { vals[k] = expf(vals[k] - m); sum += vals[k]; }
#pragma unroll
        for (int off = 32; off; off >>= 1) sum += __shfl_xor(sum, off);
        float* arow = attn + ((long)bh * 512 + (i0 + r)) * 512;
#pragma unroll
        for (int k = 0; k < 8; k++) arow[lane + 64 * k] = vals[k] / sum;
    }

    if (blockIdx.x == 0 && tid < 64) {
        int s = 0;
        for (int k = tid; k < 2048; k += 64) s += Ti[k];
#pragma unroll
        for (int off = 32; off; off >>= 1) s += __shfl_xor(s, off);
        if (tid == 0) regp[0] = 1e-3f * ((float)s / 2048.0f);
    }
}

// ---------------- Kernel 4: MFMA AV  hout = attn @ v_mean  (per b,h; fp16) ----------------
__global__ __launch_bounds__(256) void k_av(
    const float* __restrict__ attn,
    const _Float16* __restrict__ vmT,   // [bh][d][s]
    _Float16* __restrict__ hout)        // [tok][h*64+d] fp16
{
    __shared__ _Float16 Aa[4][64][8];
    __shared__ _Float16 Bb[4][64][8];
    const int i0 = blockIdx.x * 64;
    const int bh = blockIdx.y;
    const int b = bh >> 3, h = bh & 7;
    const int tid = threadIdx.x, w = tid >> 6, l = tid & 63;
    const int mB = (w & 1) * 32, nB = (w >> 1) * 32;
    const int sr = tid >> 2, sk = tid & 3;
    const int fr = l & 15, fk = l >> 4;
    const float* abase = attn + ((long)bh * 512 + i0) * 512;
    const _Float16* bbase = vmT + bh * 64 * 512;

    f32x4 acc[2][2] = {};

    float4 pa0 = *(const float4*)(abase + sr * 512 + sk * 8);
    float4 pa1 = *(const float4*)(abase + sr * 512 + sk * 8 + 4);
    uint4 pb = *(const uint4*)(bbase + sr * 512 + sk * 8);

    for (int k0 = 0; k0 < 512; k0 += 32) {
        __syncthreads();
        {
            HU8 z;
            z.h[0] = (_Float16)pa0.x; z.h[1] = (_Float16)pa0.y;
            z.h[2] = (_Float16)pa0.z; z.h[3] = (_Float16)pa0.w;
            z.h[4] = (_Float16)pa1.x; z.h[5] = (_Float16)pa1.y;
            z.h[6] = (_Float16)pa1.z; z.h[7] = (_Float16)pa1.w;
            *(uint4*)&Aa[sk][sr][0] = z.u;
            *(uint4*)&Bb[sk][sr][0] = pb;
        }
        __syncthreads();
        const int kn = (k0 + 32) & 511;
        pa0 = *(const float4*)(abase + sr * 512 + kn + sk * 8);
        pa1 = *(const float4*)(abase + sr * 512 + kn + sk * 8 + 4);
        pb = *(const uint4*)(bbase + sr * 512 + kn + sk * 8);

        f16x8 ah[2];
#pragma unroll
        for (int mt = 0; mt < 2; mt++)
            ah[mt] = *(const f16x8*)&Aa[fk][mB + mt * 16 + fr][0];
#pragma unroll
        for (int nt = 0; nt < 2; nt++) {
            f16x8 bv = *(const f16x8*)&Bb[fk][nB + nt * 16 + fr][0];
#pragma unroll
            for (int mt = 0; mt < 2; mt++)
                acc[mt][nt] = __builtin_amdgcn_mfma_f32_16x16x32_f16(ah[mt], bv, acc[mt][nt], 0, 0, 0);
        }
    }

#pragma unroll
    for (int mt = 0; mt < 2; mt++) {
#pragma unroll
        for (int nt = 0; nt < 2; nt++) {
            const int d = nB + nt * 16 + fr;
#pragma unroll
            for (int rr = 0; rr < 4; rr++) {
                const int i = i0 + mB + mt * 16 + fk * 4 + rr;
                hout[(b * 512 + i) * 512 + h * 64 + d] = (_Float16)acc[mt][nt][rr];
            }
        }
    }
}

// ---------------- Kernel 5: Wo projection, fused fp32->fp16 weight convert ----------------
// A = hout fp16 [2048][512]; B = Wo fp32 [512][512] (hi-converted in staging); Y = out + bias.
__global__ __launch_bounds__(256) void k_gemmWo(
    const _Float16* __restrict__ A, const float* __restrict__ Wo,
    const float* __restrict__ bias, float* __restrict__ Y)
{
    __shared__ _Float16 As[4][64][8];
    __shared__ _Float16 Bs[4][64][8];

    const int bn = blockIdx.x * 64, bm = blockIdx.y * 64;
    const int tid = threadIdx.x, w = tid >> 6, l = tid & 63;
    const int mB = (w & 1) * 32, nB = (w >> 1) * 32;
    const int sr = tid >> 2, sk = tid & 3;
    const int fr = l & 15, fk = l >> 4;

    f32x4 acc[2][2] = {};

    const float* bsrc = Wo + (bn + sr) * 512;
    uint4 pA = *(const uint4*)(A + (bm + sr) * 512 + sk * 8);
    float4 pb0 = *(const float4*)(bsrc + sk * 8);
    float4 pb1 = *(const float4*)(bsrc + sk * 8 + 4);

    for (int k0 = 0; k0 < 512; k0 += 32) {
        __syncthreads();
        {
            HU8 z;
            z.h[0] = (_Float16)pb0.x; z.h[1] = (_Float16)pb0.y;
            z.h[2] = (_Float16)pb0.z; z.h[3] = (_Float16)pb0.w;
            z.h[4] = (_Float16)pb1.x; z.h[5] = (_Float16)pb1.y;
            z.h[6] = (_Float16)pb1.z; z.h[7] = (_Float16)pb1.w;
            *(uint4*)&As[sk][sr][0] = pA;
            *(uint4*)&Bs[sk][sr][0] = z.u;
        }
        __syncthreads();
        const int kn = (k0 + 32) & 511;
        pA = *(const uint4*)(A + (bm + sr) * 512 + kn + sk * 8);
        pb0 = *(const float4*)(bsrc + kn + sk * 8);
        pb1 = *(const float4*)(bsrc + kn + sk * 8 + 4);

        f16x8 ah[2];
#pragma unroll
        for (int mt = 0; mt < 2; mt++)
            ah[mt] = *(const f16x8*)&As[fk][mB + mt * 16 + fr][0];
#pragma unroll
        for (int nt = 0; nt < 2; nt++) {
            f16x8 bh = *(const f16x8*)&Bs[fk][nB + nt * 16 + fr][0];
#pragma unroll
            for (int mt = 0; mt < 2; mt++)
                acc[mt][nt] = __builtin_amdgcn_mfma_f32_16x16x32_f16(ah[mt], bh, acc[mt][nt], 0, 0, 0);
        }
    }

#pragma unroll
    for (int mt = 0; mt < 2; mt++) {
#pragma unroll
        for (int nt = 0; nt < 2; nt++) {
            const int j = bn + nB + nt * 16 + fr;
            const float badd = bias[j];
#pragma unroll
            for (int rr = 0; rr < 4; rr++) {
                const int i = bm + mB + mt * 16 + fk * 4 + rr;
                Y[i * 512 + j] = acc[mt][nt][rr] + badd;
            }
        }
    }
}

extern "C" void kernel_launch(void* const* d_in, const int* in_sizes, int n_in,
                              void* d_out, int out_size, void* d_ws, size_t ws_size,
                              hipStream_t stream)
{
    const float* x    = (const float*)d_in[0];
    const float* Wq   = (const float*)d_in[1];
    const float* Wk   = (const float*)d_in[2];
    const float* Wv   = (const float*)d_in[3];
    const float* Wo   = (const float*)d_in[4];
    const float* bo   = (const float*)d_in[5];
    const float* gw1  = (const float*)d_in[6];
    const float* gb1  = (const float*)d_in[7];
    const float* gw2  = (const float*)d_in[8];
    const float* gb2  = (const float*)d_in[9];
    const float* gw3  = (const float*)d_in[10];
    const float* gb3  = (const float*)d_in[11];
    const float* cw1  = (const float*)d_in[12];
    const float* cb1  = (const float*)d_in[13];
    const float* cw2  = (const float*)d_in[14];
    const float* cb2  = (const float*)d_in[15];
    const float* alpha = (const float*)d_in[16];
    const float* beta  = (const float*)d_in[17];

    float* out   = (float*)d_out;                 // [2048*512]
    float* attn  = out + 1048576;                 // [32][512][512]
    float* regp  = out + 1048576 + 8388608;
    float* tiout = regp + 1;

    // workspace (~23.1 MB, no aliasing):
    char* ws = (char*)d_ws;
    float*    qkvh1  = (float*)ws;                            // [2048][1664] fp32, 13.63 MB
    unsigned long long* qb = (unsigned long long*)(ws + 13631488);   // 2.62 MB
    unsigned long long* kb = (unsigned long long*)(ws + 16252928);   // 2.62 MB
    _Float16* vmT    = (_Float16*)(ws + 18874368);            // 2 MB
    _Float16* hout_h = (_Float16*)(ws + 20971520);            // 2 MB
    int*      Ti     = (int*)(ws + 23068672);                 // 8 KB

    k_gemm3<<<dim3(26, 32), 256, 0, stream>>>(x, Wq, Wk, Wv, gw1, cw1, qkvh1);
    k_lif<<<dim3(32, 32), 256, 0, stream>>>(qkvh1, gb1, cb1, gw2, gb2, gw3, gb3,
                                            cw2, cb2, alpha, beta, qb, kb, vmT, Ti, tiout);
    k_scores<<<1024, 256, 0, stream>>>(qb, kb, attn, Ti, regp);
    k_av<<<dim3(8, 32), 256, 0, stream>>>(attn, vmT, hout_h);
    k_gemmWo<<<dim3(8, 32), 256, 0, stream>>>(hout_h, Wo, bo, out);
}

// Round 11
// 109.191 us; speedup vs baseline: 1.1947x; 1.1947x over previous
//
#include <hip/hip_runtime.h>
#include <cstdint>

// B=4, S=512, D=512, H=8, TM=20, DH=64
// out layout: out[1048576] | attn[8388608] | reg[1] | T_i[2048]  (all float)

typedef __attribute__((ext_vector_type(8))) _Float16 f16x8;
typedef __attribute__((ext_vector_type(4))) float f32x4;

__device__ __forceinline__ float sep_mad(float a, float b, float c) {
    // separate mul+add rounding (matches numpy), blocks FMA contraction:
    // spike threshold is discontinuous.
    float t = a * b;
    asm volatile("" : "+v"(t));
    return t + c;
}

union HU4 { _Float16 h[4]; ushort4 u; };
union HU8 { _Float16 h[8]; uint4 u; };

__device__ __forceinline__ void split4(float4 v, HU4& hi, HU4& lo) {
    hi.h[0] = (_Float16)v.x; lo.h[0] = (_Float16)(v.x - (float)hi.h[0]);
    hi.h[1] = (_Float16)v.y; lo.h[1] = (_Float16)(v.y - (float)hi.h[1]);
    hi.h[2] = (_Float16)v.z; lo.h[2] = (_Float16)(v.z - (float)hi.h[2]);
    hi.h[3] = (_Float16)v.w; lo.h[3] = (_Float16)(v.w - (float)hi.h[3]);
}

// ---------------- Kernel 1: unified fp16x3 MFMA GEMM with fused fp32->hi/lo split ----------------
// Y[2048][1664] = x @ [Wq|Wk|Wv|gw1|cw1|pad]^T, all staged fp32->fp16 hi/lo in-kernel.
// BM=BN=64, BK=32, 256 thr = 4 waves wave-tile 32x32, 3 hi/lo MFMA products.
__global__ __launch_bounds__(256) void k_gemm3(
    const float* __restrict__ X,
    const float* __restrict__ Wq, const float* __restrict__ Wk,
    const float* __restrict__ Wv, const float* __restrict__ gw1,
    const float* __restrict__ cw1,
    float* __restrict__ Y)
{
    __shared__ _Float16 AsH[4][64][8];
    __shared__ _Float16 BsH[4][64][8];
    __shared__ _Float16 AsL[4][64][8];
    __shared__ _Float16 BsL[4][64][8];

    const int bn = blockIdx.x * 64, bm = blockIdx.y * 64;
    const int tid = threadIdx.x, w = tid >> 6, l = tid & 63;
    const int mB = (w & 1) * 32, nB = (w >> 1) * 32;
    const int sr = tid >> 2, sk = tid & 3;
    const int fr = l & 15, fk = l >> 4;

    // per-thread source rows (constant across K-steps)
    const float* asrc = X + (bm + sr) * 512;
    const int brow = bn + sr;                 // concat row in [Wq|Wk|Wv|gw1|cw1|pad]
    const float* bsrc;
    bool bvalid = true;
    if      (brow < 512)  bsrc = Wq  + brow * 512;
    else if (brow < 1024) bsrc = Wk  + (brow - 512) * 512;
    else if (brow < 1536) bsrc = Wv  + (brow - 1024) * 512;
    else if (brow < 1600) bsrc = gw1 + (brow - 1536) * 512;
    else if (brow < 1632) bsrc = cw1 + (brow - 1600) * 512;
    else { bsrc = Wq; bvalid = false; }       // pad rows -> zeros

    f32x4 acc[2][2] = {};
    const float4 z4{0.f, 0.f, 0.f, 0.f};

    float4 pa0 = *(const float4*)(asrc + sk * 8);
    float4 pa1 = *(const float4*)(asrc + sk * 8 + 4);
    float4 pb0 = bvalid ? *(const float4*)(bsrc + sk * 8)     : z4;
    float4 pb1 = bvalid ? *(const float4*)(bsrc + sk * 8 + 4) : z4;

    for (int k0 = 0; k0 < 512; k0 += 32) {
        __syncthreads();
        {
            HU4 h0, l0, h1, l1;
            split4(pa0, h0, l0); split4(pa1, h1, l1);
            *(ushort4*)&AsH[sk][sr][0] = h0.u; *(ushort4*)&AsH[sk][sr][4] = h1.u;
            *(ushort4*)&AsL[sk][sr][0] = l0.u; *(ushort4*)&AsL[sk][sr][4] = l1.u;
            split4(pb0, h0, l0); split4(pb1, h1, l1);
            *(ushort4*)&BsH[sk][sr][0] = h0.u; *(ushort4*)&BsH[sk][sr][4] = h1.u;
            *(ushort4*)&BsL[sk][sr][0] = l0.u; *(ushort4*)&BsL[sk][sr][4] = l1.u;
        }
        __syncthreads();
        const int kn = (k0 + 32) & 511;   // wraps harmlessly on last iter
        pa0 = *(const float4*)(asrc + kn + sk * 8);
        pa1 = *(const float4*)(asrc + kn + sk * 8 + 4);
        if (bvalid) {
            pb0 = *(const float4*)(bsrc + kn + sk * 8);
            pb1 = *(const float4*)(bsrc + kn + sk * 8 + 4);
        }

        f16x8 ah[2], al[2];
#pragma unroll
        for (int mt = 0; mt < 2; mt++) {
            ah[mt] = *(const f16x8*)&AsH[fk][mB + mt * 16 + fr][0];
            al[mt] = *(const f16x8*)&AsL[fk][mB + mt * 16 + fr][0];
        }
#pragma unroll
        for (int nt = 0; nt < 2; nt++) {
            f16x8 bh = *(const f16x8*)&BsH[fk][nB + nt * 16 + fr][0];
            f16x8 bl = *(const f16x8*)&BsL[fk][nB + nt * 16 + fr][0];
#pragma unroll
            for (int mt = 0; mt < 2; mt++) {
                acc[mt][nt] = __builtin_amdgcn_mfma_f32_16x16x32_f16(ah[mt], bh, acc[mt][nt], 0, 0, 0);
                acc[mt][nt] = __builtin_amdgcn_mfma_f32_16x16x32_f16(ah[mt], bl, acc[mt][nt], 0, 0, 0);
                acc[mt][nt] = __builtin_amdgcn_mfma_f32_16x16x32_f16(al[mt], bh, acc[mt][nt], 0, 0, 0);
            }
        }
    }

#pragma unroll
    for (int mt = 0; mt < 2; mt++) {
#pragma unroll
        for (int nt = 0; nt < 2; nt++) {
            const int j = bn + nB + nt * 16 + fr;
#pragma unroll
            for (int rr = 0; rr < 4; rr++) {
                const int i = bm + mB + mt * 16 + fk * 4 + rr;
                Y[i * 1664 + j] = acc[mt][nt][rr];
            }
        }
    }
}

// ---------------- Kernel 2: LIF + fused gate-layers-2/3 + ballot bit-pack + v_mean transpose ----
// grid (32, 32): blockIdx.y = bh, blockIdx.x = 16-token s-block. 256 thr = 4 waves.
// Gate layers 2/3 recomputed per block (8x redundant across h, bit-identical).
// gw2 staged into padded LDS (coalesced) -- round-10's direct-global read was the 54us bug.
__global__ __launch_bounds__(256) void k_lif(
    const float* __restrict__ qkvh1,         // [2048][1664]  (q|k|v|h1raw per row)
    const float* __restrict__ gb1, const float* __restrict__ cb1,
    const float* __restrict__ gw2, const float* __restrict__ gb2,
    const float* __restrict__ gw3, const float* __restrict__ gb3,
    const float* __restrict__ cw2, const float* __restrict__ cb2,
    const float* __restrict__ pAlpha, const float* __restrict__ pBeta,
    unsigned long long* __restrict__ qbits,  // [(bh*20)+t]*512 + s
    unsigned long long* __restrict__ kbits,
    _Float16* __restrict__ vmT,              // [bh][d][s]
    int* __restrict__ Ti, float* __restrict__ ti_out)
{
    __shared__ _Float16 cnts[64][18];        // [d][s_local], pad 18 (<=2-way, free)
    __shared__ float h1s[16][100];
    __shared__ float w2s[32][65];            // pad 65: bank=(o2+k)&31, conflict-free
    __shared__ float h2s[16][36];
    __shared__ int tis[16];
    const int tid = threadIdx.x;
    const int wid = tid >> 6, lane = tid & 63;
    const int bh = blockIdx.y, s0 = blockIdx.x * 16;
    const int b = bh >> 3, h = bh & 7;
    const float alpha = pAlpha[0], beta = pBeta[0];

    // ---- stage gw2 coalesced (2048 floats), h1 activations ----
    for (int i = tid; i < 2048; i += 256) w2s[i >> 6][i & 63] = gw2[i];
    for (int i = tid; i < 1536; i += 256) {
        const int r = i / 96, c = i % 96;
        const float v = qkvh1[(long)(b * 512 + s0 + r) * 1664 + 1536 + c]
                        + (c < 64 ? gb1[c] : cb1[c - 64]);
        h1s[r][c] = fmaxf(v, 0.f);
    }
    __syncthreads();
#pragma unroll
    for (int ii = 0; ii < 2; ii++) {
        const int idx = tid + ii * 256;      // 0..511 = (tok, o2)
        const int tok = idx >> 5, o2 = idx & 31;
        float a = gb2[o2];
        for (int k = 0; k < 64; k++) a = fmaf(w2s[o2][k], h1s[tok][k], a);
        h2s[tok][o2] = fmaxf(a, 0.f);
    }
    __syncthreads();
    if (tid < 16) {
        const int tok = tid;
        float gg = gb3[0], cc = cb2[0];
        for (int k = 0; k < 32; k++) {
            gg = fmaf(gw3[k], h2s[tok][k], gg);
            cc = fmaf(cw2[k], h1s[tok][64 + k], cc);
        }
        float g = 1.f / (1.f + expf(-gg));
        float c = 1.f / (1.f + expf(-cc));
        float p1 = 0.7f * g, p2 = 0.3f * c;
        asm volatile("" : "+v"(p1), "+v"(p2));
        float comb = p1 + p2;
        float tf = ceilf(comb * 20.0f);
        tf = fminf(fmaxf(tf, 1.f), 20.f);
        tis[tok] = (int)tf;
        Ti[b * 512 + s0 + tok] = (int)tf;    // redundant x8 across h, identical values
        ti_out[b * 512 + s0 + tok] = tf;
    }
    __syncthreads();

    // ---- LIF: 4 rounds of 4 tokens ----
    const float* qrow0 = qkvh1 + (long)(b * 512 + s0 + wid) * 1664 + h * 64 + lane;
    float cq = qrow0[0], ck = qrow0[512], cv = qrow0[1024];

    for (int r = 0; r < 4; r++) {
        const int tl = r * 4 + wid;          // token_local 0..15
        const int s = s0 + tl;
        float nq = 0.f, nk = 0.f, nv = 0.f;
        if (r < 3) {
            const float* qr = qkvh1 + (long)(b * 512 + s + 4) * 1664 + h * 64 + lane;
            nq = qr[0]; nk = qr[512]; nv = qr[1024];
        }
        const int T = tis[tl];
        float iq = 0.f, vq = 0.f, ik = 0.f, vk = 0.f, iv = 0.f, vv = 0.f;
        int cnt = 0;
        const int base = (bh * 20) * 512 + s;
#pragma unroll
        for (int t = 0; t < 20; t++) {
            iq = sep_mad(alpha, iq, cq); vq = sep_mad(beta, vq, iq);
            bool sq = vq >= 1.0f; vq = sq ? 0.f : vq;
            ik = sep_mad(alpha, ik, ck); vk = sep_mad(beta, vk, ik);
            bool sk = vk >= 1.0f; vk = sk ? 0.f : vk;
            iv = sep_mad(alpha, iv, cv); vv = sep_mad(beta, vv, iv);
            bool sv = vv >= 1.0f; vv = sv ? 0.f : vv;
            bool act = t < T;
            unsigned long long mq = __ballot(sq && act);
            unsigned long long mk = __ballot(sk && act);
            if (lane == 0) {
                qbits[base + t * 512] = mq;
                kbits[base + t * 512] = mk;
            }
            cnt += (sv && act) ? 1 : 0;
        }
        cnts[lane][tl] = (_Float16)((float)cnt / 20.0f);
        cq = nq; ck = nk; cv = nv;
    }
    __syncthreads();
    // write vmT[bh][d][s0..s0+15]: thread (d = tid>>2, q = tid&3) -> 4 fp16 = 8B
    const int d = tid >> 2, q = tid & 3;
    HU4 o;
#pragma unroll
    for (int i = 0; i < 4; i++) o.h[i] = cnts[d][q * 4 + i];
    *(ushort4*)(vmT + (bh * 64 + d) * 512 + s0 + q * 4) = o.u;
}

// ---------------- Kernel 3: popcount scores + softmax -> attn (+fused reg) ----------------
__global__ __launch_bounds__(256) void k_scores(
    const unsigned long long* __restrict__ qbits,
    const unsigned long long* __restrict__ kbits,
    float* __restrict__ attn,
    const int* __restrict__ Ti, float* __restrict__ regp)
{
    const int bh = blockIdx.x >> 5;            // 0..31
    const int i0 = (blockIdx.x & 31) * 16;
    const int base = bh * 20 * 512;
    __shared__ unsigned long long qs[20][16];
    __shared__ float sc[16][512];
    const int tid = threadIdx.x;
    for (int idx = tid; idx < 320; idx += 256) {
        int t = idx >> 4, r = idx & 15;
        qs[t][r] = qbits[base + t * 512 + i0 + r];
    }
    int Tmax = 0;
    const int tb = (bh >> 3) * 512 + i0;
#pragma unroll
    for (int r = 0; r < 16; r++) Tmax = max(Tmax, Ti[tb + r]);
    __syncthreads();

    {
        // thread handles adjacent j-pair (2*tid, 2*tid+1): 16B kbits loads
        const unsigned long long* kbp = kbits + base + 2 * tid;
        int acc0[16] = {}, acc1[16] = {};
        for (int tc = 0; tc < 4; tc++) {
            if (tc * 5 >= Tmax) break;
            unsigned long long kv0[5], kv1[5];
#pragma unroll
            for (int t = 0; t < 5; t++) {
                ulonglong2 kk = *(const ulonglong2*)(kbp + (tc * 5 + t) * 512);
                kv0[t] = kk.x; kv1[t] = kk.y;
            }
#pragma unroll
            for (int r = 0; r < 16; r++) {
#pragma unroll
                for (int t = 0; t < 5; t++) {
                    unsigned long long qv = qs[tc * 5 + t][r];
                    acc0[r] += __popcll(qv & kv0[t]);
                    acc1[r] += __popcll(qv & kv1[t]);
                }
            }
        }
#pragma unroll
        for (int r = 0; r < 16; r++) {
            sc[r][2 * tid]     = (float)acc0[r] * 0.125f;
            sc[r][2 * tid + 1] = (float)acc1[r] * 0.125f;
        }
    }
    __syncthreads();

    const int wid = tid >> 6, lane = tid & 63;
#pragma unroll
    for (int rr = 0; rr < 4; rr++) {
        const int r = wid * 4 + rr;
        float vals[8];
        float m = -1e30f;
#pragma unroll
        for (int k = 0; k < 8; k++) { vals[k] = sc[r][lane + 64 * k]; m = fmaxf(m, vals[k]); }
#pragma unroll
        for (int off = 32; off; off >>= 1) m = fmaxf(m, __shfl_xor(m, off));
        float sum = 0.f;
#pragma unroll
        for (int k = 0; k < 8; k++) { vals[k] = expf(vals[k] - m); sum += vals[k]; }
#pragma unroll
        for (int off = 32; off; off >>= 1) sum += __shfl_xor(sum, off);
        float* arow = attn + ((long)bh * 512 + (i0 + r)) * 512;
#pragma unroll
        for (int k = 0; k < 8; k++) arow[lane + 64 * k] = vals[k] / sum;
    }

    if (blockIdx.x == 0 && tid < 64) {
        int s = 0;
        for (int k = tid; k < 2048; k += 64) s += Ti[k];
#pragma unroll
        for (int off = 32; off; off >>= 1) s += __shfl_xor(s, off);
        if (tid == 0) regp[0] = 1e-3f * ((float)s / 2048.0f);
    }
}

// ---------------- Kernel 4: MFMA AV  hout = attn @ v_mean  (per b,h; fp16) ----------------
__global__ __launch_bounds__(256) void k_av(
    const float* __restrict__ attn,
    const _Float16* __restrict__ vmT,   // [bh][d][s]
    _Float16* __restrict__ hout)        // [tok][h*64+d] fp16
{
    __shared__ _Float16 Aa[4][64][8];
    __shared__ _Float16 Bb[4][64][8];
    const int i0 = blockIdx.x * 64;
    const int bh = blockIdx.y;
    const int b = bh >> 3, h = bh & 7;
    const int tid = threadIdx.x, w = tid >> 6, l = tid & 63;
    const int mB = (w & 1) * 32, nB = (w >> 1) * 32;
    const int sr = tid >> 2, sk = tid & 3;
    const int fr = l & 15, fk = l >> 4;
    const float* abase = attn + ((long)bh * 512 + i0) * 512;
    const _Float16* bbase = vmT + bh * 64 * 512;

    f32x4 acc[2][2] = {};

    float4 pa0 = *(const float4*)(abase + sr * 512 + sk * 8);
    float4 pa1 = *(const float4*)(abase + sr * 512 + sk * 8 + 4);
    uint4 pb = *(const uint4*)(bbase + sr * 512 + sk * 8);

    for (int k0 = 0; k0 < 512; k0 += 32) {
        __syncthreads();
        {
            HU8 z;
            z.h[0] = (_Float16)pa0.x; z.h[1] = (_Float16)pa0.y;
            z.h[2] = (_Float16)pa0.z; z.h[3] = (_Float16)pa0.w;
            z.h[4] = (_Float16)pa1.x; z.h[5] = (_Float16)pa1.y;
            z.h[6] = (_Float16)pa1.z; z.h[7] = (_Float16)pa1.w;
            *(uint4*)&Aa[sk][sr][0] = z.u;
            *(uint4*)&Bb[sk][sr][0] = pb;
        }
        __syncthreads();
        const int kn = (k0 + 32) & 511;
        pa0 = *(const float4*)(abase + sr * 512 + kn + sk * 8);
        pa1 = *(const float4*)(abase + sr * 512 + kn + sk * 8 + 4);
        pb = *(const uint4*)(bbase + sr * 512 + kn + sk * 8);

        f16x8 ah[2];
#pragma unroll
        for (int mt = 0; mt < 2; mt++)
            ah[mt] = *(const f16x8*)&Aa[fk][mB + mt * 16 + fr][0];
#pragma unroll
        for (int nt = 0; nt < 2; nt++) {
            f16x8 bv = *(const f16x8*)&Bb[fk][nB + nt * 16 + fr][0];
#pragma unroll
            for (int mt = 0; mt < 2; mt++)
                acc[mt][nt] = __builtin_amdgcn_mfma_f32_16x16x32_f16(ah[mt], bv, acc[mt][nt], 0, 0, 0);
        }
    }

#pragma unroll
    for (int mt = 0; mt < 2; mt++) {
#pragma unroll
        for (int nt = 0; nt < 2; nt++) {
            const int d = nB + nt * 16 + fr;
#pragma unroll
            for (int rr = 0; rr < 4; rr++) {
                const int i = i0 + mB + mt * 16 + fk * 4 + rr;
                hout[(b * 512 + i) * 512 + h * 64 + d] = (_Float16)acc[mt][nt][rr];
            }
        }
    }
}

// ---------------- Kernel 5: Wo projection, fused fp32->fp16 weight convert ----------------
// A = hout fp16 [2048][512]; B = Wo fp32 [512][512] (hi-converted in staging); Y = out + bias.
__global__ __launch_bounds__(256) void k_gemmWo(
    const _Float16* __restrict__ A, const float* __restrict__ Wo,
    const float* __restrict__ bias, float* __restrict__ Y)
{
    __shared__ _Float16 As[4][64][8];
    __shared__ _Float16 Bs[4][64][8];

    const int bn = blockIdx.x * 64, bm = blockIdx.y * 64;
    const int tid = threadIdx.x, w = tid >> 6, l = tid & 63;
    const int mB = (w & 1) * 32, nB = (w >> 1) * 32;
    const int sr = tid >> 2, sk = tid & 3;
    const int fr = l & 15, fk = l >> 4;

    f32x4 acc[2][2] = {};

    const float* bsrc = Wo + (bn + sr) * 512;
    uint4 pA = *(const uint4*)(A + (bm + sr) * 512 + sk * 8);
    float4 pb0 = *(const float4*)(bsrc + sk * 8);
    float4 pb1 = *(const float4*)(bsrc + sk * 8 + 4);

    for (int k0 = 0; k0 < 512; k0 += 32) {
        __syncthreads();
        {
            HU8 z;
            z.h[0] = (_Float16)pb0.x; z.h[1] = (_Float16)pb0.y;
            z.h[2] = (_Float16)pb0.z; z.h[3] = (_Float16)pb0.w;
            z.h[4] = (_Float16)pb1.x; z.h[5] = (_Float16)pb1.y;
            z.h[6] = (_Float16)pb1.z; z.h[7] = (_Float16)pb1.w;
            *(uint4*)&As[sk][sr][0] = pA;
            *(uint4*)&Bs[sk][sr][0] = z.u;
        }
        __syncthreads();
        const int kn = (k0 + 32) & 511;
        pA = *(const uint4*)(A + (bm + sr) * 512 + kn + sk * 8);
        pb0 = *(const float4*)(bsrc + kn + sk * 8);
        pb1 = *(const float4*)(bsrc + kn + sk * 8 + 4);

        f16x8 ah[2];
#pragma unroll
        for (int mt = 0; mt < 2; mt++)
            ah[mt] = *(const f16x8*)&As[fk][mB + mt * 16 + fr][0];
#pragma unroll
        for (int nt = 0; nt < 2; nt++) {
            f16x8 bh = *(const f16x8*)&Bs[fk][nB + nt * 16 + fr][0];
#pragma unroll
            for (int mt = 0; mt < 2; mt++)
                acc[mt][nt] = __builtin_amdgcn_mfma_f32_16x16x32_f16(ah[mt], bh, acc[mt][nt], 0, 0, 0);
        }
    }

#pragma unroll
    for (int mt = 0; mt < 2; mt++) {
#pragma unroll
        for (int nt = 0; nt < 2; nt++) {
            const int j = bn + nB + nt * 16 + fr;
            const float badd = bias[j];
#pragma unroll
            for (int rr = 0; rr < 4; rr++) {
                const int i = bm + mB + mt * 16 + fk * 4 + rr;
                Y[i * 512 + j] = acc[mt][nt][rr] + badd;
            }
        }
    }
}

extern "C" void kernel_launch(void* const* d_in, const int* in_sizes, int n_in,
                              void* d_out, int out_size, void* d_ws, size_t ws_size,
                              hipStream_t stream)
{
    const float* x    = (const float*)d_in[0];
    const float* Wq   = (const float*)d_in[1];
    const float* Wk   = (const float*)d_in[2];
    const float* Wv   = (const float*)d_in[3];
    const float* Wo   = (const float*)d_in[4];
    const float* bo   = (const float*)d_in[5];
    const float* gw1  = (const float*)d_in[6];
    const float* gb1  = (const float*)d_in[7];
    const float* gw2  = (const float*)d_in[8];
    const float* gb2  = (const float*)d_in[9];
    const float* gw3  = (const float*)d_in[10];
    const float* gb3  = (const float*)d_in[11];
    const float* cw1  = (const float*)d_in[12];
    const float* cb1  = (const float*)d_in[13];
    const float* cw2  = (const float*)d_in[14];
    const float* cb2  = (const float*)d_in[15];
    const float* alpha = (const float*)d_in[16];
    const float* beta  = (const float*)d_in[17];

    float* out   = (float*)d_out;                 // [2048*512]
    float* attn  = out + 1048576;                 // [32][512][512]
    float* regp  = out + 1048576 + 8388608;
    float* tiout = regp + 1;

    // workspace (~23.1 MB, no aliasing):
    char* ws = (char*)d_ws;
    float*    qkvh1  = (float*)ws;                            // [2048][1664] fp32, 13.63 MB
    unsigned long long* qb = (unsigned long long*)(ws + 13631488);   // 2.62 MB
    unsigned long long* kb = (unsigned long long*)(ws + 16252928);   // 2.62 MB
    _Float16* vmT    = (_Float16*)(ws + 18874368);            // 2 MB
    _Float16* hout_h = (_Float16*)(ws + 20971520);            // 2 MB
    int*      Ti     = (int*)(ws + 23068672);                 // 8 KB

    k_gemm3<<<dim3(26, 32), 256, 0, stream>>>(x, Wq, Wk, Wv, gw1, cw1, qkvh1);
    k_lif<<<dim3(32, 32), 256, 0, stream>>>(qkvh1, gb1, cb1, gw2, gb2, gw3, gb3,
                                            cw2, cb2, alpha, beta, qb, kb, vmT, Ti, tiout);
    k_scores<<<1024, 256, 0, stream>>>(qb, kb, attn, Ti, regp);
    k_av<<<dim3(8, 32), 256, 0, stream>>>(attn, vmT, hout_h);
    k_gemmWo<<<dim3(8, 32), 256, 0, stream>>>(hout_h, Wo, bo, out);
}

// Round 12
// 95.404 us; speedup vs baseline: 1.3674x; 1.1445x over previous
//
#include <hip/hip_runtime.h>
#include <cstdint>

// B=4, S=512, D=512, H=8, TM=20, DH=64
// out layout: out[1048576] | attn[8388608] | reg[1] | T_i[2048]  (all float)

typedef __attribute__((ext_vector_type(8))) _Float16 f16x8;
typedef __attribute__((ext_vector_type(4))) float f32x4;

__device__ __forceinline__ float sep_mad(float a, float b, float c) {
    // separate mul+add rounding (matches numpy), blocks FMA contraction:
    // spike threshold is discontinuous.
    float t = a * b;
    asm volatile("" : "+v"(t));
    return t + c;
}

union HU4 { _Float16 h[4]; ushort4 u; };
union HU8 { _Float16 h[8]; uint4 u; };
union HU2 { _Float16 h[2]; unsigned u; };

__device__ __forceinline__ void split4(float4 v, HU4& hi, HU4& lo) {
    hi.h[0] = (_Float16)v.x; lo.h[0] = (_Float16)(v.x - (float)hi.h[0]);
    hi.h[1] = (_Float16)v.y; lo.h[1] = (_Float16)(v.y - (float)hi.h[1]);
    hi.h[2] = (_Float16)v.z; lo.h[2] = (_Float16)(v.z - (float)hi.h[2]);
    hi.h[3] = (_Float16)v.w; lo.h[3] = (_Float16)(v.w - (float)hi.h[3]);
}

__device__ __forceinline__ void cast4(float4 v, HU4& hi) {
    hi.h[0] = (_Float16)v.x; hi.h[1] = (_Float16)v.y;
    hi.h[2] = (_Float16)v.z; hi.h[3] = (_Float16)v.w;
}

// ---------------- Kernel 1: mixed-precision MFMA GEMM, fused fp32->fp16 split ----------------
// Y[2048][1664] = x @ [Wq|Wk|Wv|gw1|cw1|pad]^T.
// QKV N-blocks (bn<1536): plain fp16 (proven r5/r6, absmax 0.146).
// Gate N-blocks (bn>=1536): fp16x3 hi/lo -- T_i must be exact.
__global__ __launch_bounds__(256) void k_gemm3(
    const float* __restrict__ X,
    const float* __restrict__ Wq, const float* __restrict__ Wk,
    const float* __restrict__ Wv, const float* __restrict__ gw1,
    const float* __restrict__ cw1,
    float* __restrict__ Y)
{
    __shared__ _Float16 AsH[4][64][8];
    __shared__ _Float16 BsH[4][64][8];
    __shared__ _Float16 AsL[4][64][8];
    __shared__ _Float16 BsL[4][64][8];

    const int bn = blockIdx.x * 64, bm = blockIdx.y * 64;
    const int tid = threadIdx.x, w = tid >> 6, l = tid & 63;
    const int mB = (w & 1) * 32, nB = (w >> 1) * 32;
    const int sr = tid >> 2, sk = tid & 3;
    const int fr = l & 15, fk = l >> 4;
    const bool gate = (bn >= 1536);           // block-uniform

    const float* asrc = X + (bm + sr) * 512;
    const int brow = bn + sr;
    const float* bsrc;
    bool bvalid = true;
    if      (brow < 512)  bsrc = Wq  + brow * 512;
    else if (brow < 1024) bsrc = Wk  + (brow - 512) * 512;
    else if (brow < 1536) bsrc = Wv  + (brow - 1024) * 512;
    else if (brow < 1600) bsrc = gw1 + (brow - 1536) * 512;
    else if (brow < 1632) bsrc = cw1 + (brow - 1600) * 512;
    else { bsrc = Wq; bvalid = false; }

    f32x4 acc[2][2] = {};
    const float4 z4{0.f, 0.f, 0.f, 0.f};

    float4 pa0 = *(const float4*)(asrc + sk * 8);
    float4 pa1 = *(const float4*)(asrc + sk * 8 + 4);
    float4 pb0 = bvalid ? *(const float4*)(bsrc + sk * 8)     : z4;
    float4 pb1 = bvalid ? *(const float4*)(bsrc + sk * 8 + 4) : z4;

    for (int k0 = 0; k0 < 512; k0 += 32) {
        __syncthreads();
        if (gate) {
            HU4 h0, l0, h1, l1;
            split4(pa0, h0, l0); split4(pa1, h1, l1);
            *(ushort4*)&AsH[sk][sr][0] = h0.u; *(ushort4*)&AsH[sk][sr][4] = h1.u;
            *(ushort4*)&AsL[sk][sr][0] = l0.u; *(ushort4*)&AsL[sk][sr][4] = l1.u;
            split4(pb0, h0, l0); split4(pb1, h1, l1);
            *(ushort4*)&BsH[sk][sr][0] = h0.u; *(ushort4*)&BsH[sk][sr][4] = h1.u;
            *(ushort4*)&BsL[sk][sr][0] = l0.u; *(ushort4*)&BsL[sk][sr][4] = l1.u;
        } else {
            HU4 h0, h1;
            cast4(pa0, h0); cast4(pa1, h1);
            *(ushort4*)&AsH[sk][sr][0] = h0.u; *(ushort4*)&AsH[sk][sr][4] = h1.u;
            cast4(pb0, h0); cast4(pb1, h1);
            *(ushort4*)&BsH[sk][sr][0] = h0.u; *(ushort4*)&BsH[sk][sr][4] = h1.u;
        }
        __syncthreads();
        const int kn = (k0 + 32) & 511;   // wraps harmlessly on last iter
        pa0 = *(const float4*)(asrc + kn + sk * 8);
        pa1 = *(const float4*)(asrc + kn + sk * 8 + 4);
        if (bvalid) {
            pb0 = *(const float4*)(bsrc + kn + sk * 8);
            pb1 = *(const float4*)(bsrc + kn + sk * 8 + 4);
        }

        f16x8 ah[2];
#pragma unroll
        for (int mt = 0; mt < 2; mt++)
            ah[mt] = *(const f16x8*)&AsH[fk][mB + mt * 16 + fr][0];
        if (gate) {
            f16x8 al[2];
#pragma unroll
            for (int mt = 0; mt < 2; mt++)
                al[mt] = *(const f16x8*)&AsL[fk][mB + mt * 16 + fr][0];
#pragma unroll
            for (int nt = 0; nt < 2; nt++) {
                f16x8 bh = *(const f16x8*)&BsH[fk][nB + nt * 16 + fr][0];
                f16x8 bl = *(const f16x8*)&BsL[fk][nB + nt * 16 + fr][0];
#pragma unroll
                for (int mt = 0; mt < 2; mt++) {
                    acc[mt][nt] = __builtin_amdgcn_mfma_f32_16x16x32_f16(ah[mt], bh, acc[mt][nt], 0, 0, 0);
                    acc[mt][nt] = __builtin_amdgcn_mfma_f32_16x16x32_f16(ah[mt], bl, acc[mt][nt], 0, 0, 0);
                    acc[mt][nt] = __builtin_amdgcn_mfma_f32_16x16x32_f16(al[mt], bh, acc[mt][nt], 0, 0, 0);
                }
            }
        } else {
#pragma unroll
            for (int nt = 0; nt < 2; nt++) {
                f16x8 bh = *(const f16x8*)&BsH[fk][nB + nt * 16 + fr][0];
#pragma unroll
                for (int mt = 0; mt < 2; mt++)
                    acc[mt][nt] = __builtin_amdgcn_mfma_f32_16x16x32_f16(ah[mt], bh, acc[mt][nt], 0, 0, 0);
            }
        }
    }

#pragma unroll
    for (int mt = 0; mt < 2; mt++) {
#pragma unroll
        for (int nt = 0; nt < 2; nt++) {
            const int j = bn + nB + nt * 16 + fr;
#pragma unroll
            for (int rr = 0; rr < 4; rr++) {
                const int i = bm + mB + mt * 16 + fk * 4 + rr;
                Y[i * 1664 + j] = acc[mt][nt][rr];
            }
        }
    }
}

// ---------------- Kernel 2: LIF + fused gate-layers-2/3 + ballot bit-pack + v_mean transpose ----
// grid (32, 32): blockIdx.y = bh, blockIdx.x = 16-token s-block. 256 thr = 4 waves.
__global__ __launch_bounds__(256) void k_lif(
    const float* __restrict__ qkvh1,         // [2048][1664]  (q|k|v|h1raw per row)
    const float* __restrict__ gb1, const float* __restrict__ cb1,
    const float* __restrict__ gw2, const float* __restrict__ gb2,
    const float* __restrict__ gw3, const float* __restrict__ gb3,
    const float* __restrict__ cw2, const float* __restrict__ cb2,
    const float* __restrict__ pAlpha, const float* __restrict__ pBeta,
    unsigned long long* __restrict__ qbits,  // [(bh*20)+t]*512 + s
    unsigned long long* __restrict__ kbits,
    _Float16* __restrict__ vmT,              // [bh][d][s]
    int* __restrict__ Ti, float* __restrict__ ti_out)
{
    __shared__ _Float16 cnts[64][18];        // [d][s_local], pad 18 (<=2-way, free)
    __shared__ float h1s[16][100];
    __shared__ float w2s[32][65];            // pad 65: conflict-free
    __shared__ float h2s[16][36];
    __shared__ int tis[16];
    const int tid = threadIdx.x;
    const int wid = tid >> 6, lane = tid & 63;
    const int bh = blockIdx.y, s0 = blockIdx.x * 16;
    const int b = bh >> 3, h = bh & 7;
    const float alpha = pAlpha[0], beta = pBeta[0];

    for (int i = tid; i < 2048; i += 256) w2s[i >> 6][i & 63] = gw2[i];
    for (int i = tid; i < 1536; i += 256) {
        const int r = i / 96, c = i % 96;
        const float v = qkvh1[(long)(b * 512 + s0 + r) * 1664 + 1536 + c]
                        + (c < 64 ? gb1[c] : cb1[c - 64]);
        h1s[r][c] = fmaxf(v, 0.f);
    }
    __syncthreads();
#pragma unroll
    for (int ii = 0; ii < 2; ii++) {
        const int idx = tid + ii * 256;      // 0..511 = (tok, o2)
        const int tok = idx >> 5, o2 = idx & 31;
        float a = gb2[o2];
        for (int k = 0; k < 64; k++) a = fmaf(w2s[o2][k], h1s[tok][k], a);
        h2s[tok][o2] = fmaxf(a, 0.f);
    }
    __syncthreads();
    if (tid < 16) {
        const int tok = tid;
        float gg = gb3[0], cc = cb2[0];
        for (int k = 0; k < 32; k++) {
            gg = fmaf(gw3[k], h2s[tok][k], gg);
            cc = fmaf(cw2[k], h1s[tok][64 + k], cc);
        }
        float g = 1.f / (1.f + expf(-gg));
        float c = 1.f / (1.f + expf(-cc));
        float p1 = 0.7f * g, p2 = 0.3f * c;
        asm volatile("" : "+v"(p1), "+v"(p2));
        float comb = p1 + p2;
        float tf = ceilf(comb * 20.0f);
        tf = fminf(fmaxf(tf, 1.f), 20.f);
        tis[tok] = (int)tf;
        Ti[b * 512 + s0 + tok] = (int)tf;
        ti_out[b * 512 + s0 + tok] = tf;
    }
    __syncthreads();

    const float* qrow0 = qkvh1 + (long)(b * 512 + s0 + wid) * 1664 + h * 64 + lane;
    float cq = qrow0[0], ck = qrow0[512], cv = qrow0[1024];

    for (int r = 0; r < 4; r++) {
        const int tl = r * 4 + wid;          // token_local 0..15
        const int s = s0 + tl;
        float nq = 0.f, nk = 0.f, nv = 0.f;
        if (r < 3) {
            const float* qr = qkvh1 + (long)(b * 512 + s + 4) * 1664 + h * 64 + lane;
            nq = qr[0]; nk = qr[512]; nv = qr[1024];
        }
        const int T = tis[tl];
        float iq = 0.f, vq = 0.f, ik = 0.f, vk = 0.f, iv = 0.f, vv = 0.f;
        int cnt = 0;
        const int base = (bh * 20) * 512 + s;
#pragma unroll
        for (int t = 0; t < 20; t++) {
            iq = sep_mad(alpha, iq, cq); vq = sep_mad(beta, vq, iq);
            bool sq = vq >= 1.0f; vq = sq ? 0.f : vq;
            ik = sep_mad(alpha, ik, ck); vk = sep_mad(beta, vk, ik);
            bool sk = vk >= 1.0f; vk = sk ? 0.f : vk;
            iv = sep_mad(alpha, iv, cv); vv = sep_mad(beta, vv, iv);
            bool sv = vv >= 1.0f; vv = sv ? 0.f : vv;
            bool act = t < T;
            unsigned long long mq = __ballot(sq && act);
            unsigned long long mk = __ballot(sk && act);
            if (lane == 0) {
                qbits[base + t * 512] = mq;
                kbits[base + t * 512] = mk;
            }
            cnt += (sv && act) ? 1 : 0;
        }
        cnts[lane][tl] = (_Float16)((float)cnt / 20.0f);
        cq = nq; ck = nk; cv = nv;
    }
    __syncthreads();
    const int d = tid >> 2, q = tid & 3;
    HU4 o;
#pragma unroll
    for (int i = 0; i < 4; i++) o.h[i] = cnts[d][q * 4 + i];
    *(ushort4*)(vmT + (bh * 64 + d) * 512 + s0 + q * 4) = o.u;
}

// ---------------- Kernel 3: popcount scores + softmax -> attn + fused AV -> hout ----------------
// Block = (bh, 16 q-rows). After softmax the 16x512 attn tile is in LDS (fp16, exact
// conversion identical to old k_av staging) -> each wave MFMAs a 16x16 d-tile of hout.
__global__ __launch_bounds__(256) void k_scores_av(
    const unsigned long long* __restrict__ qbits,
    const unsigned long long* __restrict__ kbits,
    float* __restrict__ attn,
    const int* __restrict__ Ti, float* __restrict__ regp,
    const _Float16* __restrict__ vmT,   // [bh][d][s]
    _Float16* __restrict__ hout)        // [tok][h*64+d] fp16
{
    const int bh = blockIdx.x >> 5;            // 0..31
    const int i0 = (blockIdx.x & 31) * 16;
    const int base = bh * 20 * 512;
    __shared__ unsigned long long qs[20][16];
    __shared__ _Float16 sc16[16][520];         // pad 520: rows 1040B, 16B-aligned
    const int tid = threadIdx.x;
    for (int idx = tid; idx < 320; idx += 256) {
        int t = idx >> 4, r = idx & 15;
        qs[t][r] = qbits[base + t * 512 + i0 + r];
    }
    int Tmax = 0;
    const int tb = (bh >> 3) * 512 + i0;
#pragma unroll
    for (int r = 0; r < 16; r++) Tmax = max(Tmax, Ti[tb + r]);
    __syncthreads();

    {
        const unsigned long long* kbp = kbits + base + 2 * tid;
        int acc0[16] = {}, acc1[16] = {};
        for (int tc = 0; tc < 4; tc++) {
            if (tc * 5 >= Tmax) break;
            unsigned long long kv0[5], kv1[5];
#pragma unroll
            for (int t = 0; t < 5; t++) {
                ulonglong2 kk = *(const ulonglong2*)(kbp + (tc * 5 + t) * 512);
                kv0[t] = kk.x; kv1[t] = kk.y;
            }
#pragma unroll
            for (int r = 0; r < 16; r++) {
#pragma unroll
                for (int t = 0; t < 5; t++) {
                    unsigned long long qv = qs[tc * 5 + t][r];
                    acc0[r] += __popcll(qv & kv0[t]);
                    acc1[r] += __popcll(qv & kv1[t]);
                }
            }
        }
#pragma unroll
        for (int r = 0; r < 16; r++) {
            HU2 p;                              // counts <= 1280: *0.125 exact in fp16
            p.h[0] = (_Float16)((float)acc0[r] * 0.125f);
            p.h[1] = (_Float16)((float)acc1[r] * 0.125f);
            *(unsigned*)&sc16[r][2 * tid] = p.u;
        }
    }
    __syncthreads();

    const int wid = tid >> 6, lane = tid & 63;
#pragma unroll
    for (int rr = 0; rr < 4; rr++) {
        const int r = wid * 4 + rr;
        float vals[8];
        float m = -1e30f;
#pragma unroll
        for (int k = 0; k < 8; k++) { vals[k] = (float)sc16[r][lane + 64 * k]; m = fmaxf(m, vals[k]); }
#pragma unroll
        for (int off = 32; off; off >>= 1) m = fmaxf(m, __shfl_xor(m, off));
        float sum = 0.f;
#pragma unroll
        for (int k = 0; k < 8; k++) { vals[k] = expf(vals[k] - m); sum += vals[k]; }
#pragma unroll
        for (int off = 32; off; off >>= 1) sum += __shfl_xor(sum, off);
        float* arow = attn + ((long)bh * 512 + (i0 + r)) * 512;
#pragma unroll
        for (int k = 0; k < 8; k++) {
            const float o = vals[k] / sum;
            arow[lane + 64 * k] = o;
            sc16[r][lane + 64 * k] = (_Float16)o;   // same conversion old k_av applied
        }
    }

    if (blockIdx.x == 0 && tid < 64) {
        int s = 0;
        for (int k = tid; k < 2048; k += 64) s += Ti[k];
#pragma unroll
        for (int off = 32; off; off >>= 1) s += __shfl_xor(s, off);
        if (tid == 0) regp[0] = 1e-3f * ((float)s / 2048.0f);
    }
    __syncthreads();

    // ---- fused AV: wave wid handles d-tile [wid*16, wid*16+16) ----
    const int fr = lane & 15, fk = lane >> 4;
    const int b = bh >> 3, h = bh & 7;
    f32x4 acc = {};
    const _Float16* bsrc = vmT + (bh * 64 + wid * 16 + fr) * 512;
#pragma unroll
    for (int k0 = 0; k0 < 512; k0 += 32) {
        f16x8 av = *(const f16x8*)&sc16[fr][k0 + fk * 8];
        f16x8 bv = *(const f16x8*)(bsrc + k0 + fk * 8);
        acc = __builtin_amdgcn_mfma_f32_16x16x32_f16(av, bv, acc, 0, 0, 0);
    }
    const int d = wid * 16 + fr;
#pragma unroll
    for (int rr = 0; rr < 4; rr++) {
        const int i = i0 + fk * 4 + rr;
        hout[(b * 512 + i) * 512 + h * 64 + d] = (_Float16)acc[rr];
    }
}

// ---------------- Kernel 4: Wo projection, fused fp32->fp16 weight convert ----------------
__global__ __launch_bounds__(256) void k_gemmWo(
    const _Float16* __restrict__ A, const float* __restrict__ Wo,
    const float* __restrict__ bias, float* __restrict__ Y)
{
    __shared__ _Float16 As[4][64][8];
    __shared__ _Float16 Bs[4][64][8];

    const int bn = blockIdx.x * 64, bm = blockIdx.y * 64;
    const int tid = threadIdx.x, w = tid >> 6, l = tid & 63;
    const int mB = (w & 1) * 32, nB = (w >> 1) * 32;
    const int sr = tid >> 2, sk = tid & 3;
    const int fr = l & 15, fk = l >> 4;

    f32x4 acc[2][2] = {};

    const float* bsrc = Wo + (bn + sr) * 512;
    uint4 pA = *(const uint4*)(A + (bm + sr) * 512 + sk * 8);
    float4 pb0 = *(const float4*)(bsrc + sk * 8);
    float4 pb1 = *(const float4*)(bsrc + sk * 8 + 4);

    for (int k0 = 0; k0 < 512; k0 += 32) {
        __syncthreads();
        {
            HU4 h0, h1;
            cast4(pb0, h0); cast4(pb1, h1);
            *(uint4*)&As[sk][sr][0] = pA;
            *(ushort4*)&Bs[sk][sr][0] = h0.u; *(ushort4*)&Bs[sk][sr][4] = h1.u;
        }
        __syncthreads();
        const int kn = (k0 + 32) & 511;
        pA = *(const uint4*)(A + (bm + sr) * 512 + kn + sk * 8);
        pb0 = *(const float4*)(bsrc + kn + sk * 8);
        pb1 = *(const float4*)(bsrc + kn + sk * 8 + 4);

        f16x8 ah[2];
#pragma unroll
        for (int mt = 0; mt < 2; mt++)
            ah[mt] = *(const f16x8*)&As[fk][mB + mt * 16 + fr][0];
#pragma unroll
        for (int nt = 0; nt < 2; nt++) {
            f16x8 bh = *(const f16x8*)&Bs[fk][nB + nt * 16 + fr][0];
#pragma unroll
            for (int mt = 0; mt < 2; mt++)
                acc[mt][nt] = __builtin_amdgcn_mfma_f32_16x16x32_f16(ah[mt], bh, acc[mt][nt], 0, 0, 0);
        }
    }

#pragma unroll
    for (int mt = 0; mt < 2; mt++) {
#pragma unroll
        for (int nt = 0; nt < 2; nt++) {
            const int j = bn + nB + nt * 16 + fr;
            const float badd = bias[j];
#pragma unroll
            for (int rr = 0; rr < 4; rr++) {
                const int i = bm + mB + mt * 16 + fk * 4 + rr;
                Y[i * 512 + j] = acc[mt][nt][rr] + badd;
            }
        }
    }
}

extern "C" void kernel_launch(void* const* d_in, const int* in_sizes, int n_in,
                              void* d_out, int out_size, void* d_ws, size_t ws_size,
                              hipStream_t stream)
{
    const float* x    = (const float*)d_in[0];
    const float* Wq   = (const float*)d_in[1];
    const float* Wk   = (const float*)d_in[2];
    const float* Wv   = (const float*)d_in[3];
    const float* Wo   = (const float*)d_in[4];
    const float* bo   = (const float*)d_in[5];
    const float* gw1  = (const float*)d_in[6];
    const float* gb1  = (const float*)d_in[7];
    const float* gw2  = (const float*)d_in[8];
    const float* gb2  = (const float*)d_in[9];
    const float* gw3  = (const float*)d_in[10];
    const float* gb3  = (const float*)d_in[11];
    const float* cw1  = (const float*)d_in[12];
    const float* cb1  = (const float*)d_in[13];
    const float* cw2  = (const float*)d_in[14];
    const float* cb2  = (const float*)d_in[15];
    const float* alpha = (const float*)d_in[16];
    const float* beta  = (const float*)d_in[17];

    float* out   = (float*)d_out;                 // [2048*512]
    float* attn  = out + 1048576;                 // [32][512][512]
    float* regp  = out + 1048576 + 8388608;
    float* tiout = regp + 1;

    // workspace (~23.1 MB, no aliasing):
    char* ws = (char*)d_ws;
    float*    qkvh1  = (float*)ws;                            // [2048][1664] fp32, 13.63 MB
    unsigned long long* qb = (unsigned long long*)(ws + 13631488);   // 2.62 MB
    unsigned long long* kb = (unsigned long long*)(ws + 16252928);   // 2.62 MB
    _Float16* vmT    = (_Float16*)(ws + 18874368);            // 2 MB
    _Float16* hout_h = (_Float16*)(ws + 20971520);            // 2 MB
    int*      Ti     = (int*)(ws + 23068672);                 // 8 KB

    k_gemm3<<<dim3(26, 32), 256, 0, stream>>>(x, Wq, Wk, Wv, gw1, cw1, qkvh1);
    k_lif<<<dim3(32, 32), 256, 0, stream>>>(qkvh1, gb1, cb1, gw2, gb2, gw3, gb3,
                                            cw2, cb2, alpha, beta, qb, kb, vmT, Ti, tiout);
    k_scores_av<<<1024, 256, 0, stream>>>(qb, kb, attn, Ti, regp, vmT, hout_h);
    k_gemmWo<<<dim3(8, 32), 256, 0, stream>>>(hout_h, Wo, bo, out);
}

// Round 13
// 94.125 us; speedup vs baseline: 1.3860x; 1.0136x over previous
//
#include <hip/hip_runtime.h>
#include <cstdint>

// B=4, S=512, D=512, H=8, TM=20, DH=64
// out layout: out[1048576] | attn[8388608] | reg[1] | T_i[2048]  (all float)

typedef __attribute__((ext_vector_type(8))) _Float16 f16x8;
typedef __attribute__((ext_vector_type(4))) float f32x4;

__device__ __forceinline__ float sep_mad(float a, float b, float c) {
    // separate mul+add rounding (matches numpy), blocks FMA contraction:
    // spike threshold is discontinuous.
    float t = a * b;
    asm volatile("" : "+v"(t));
    return t + c;
}

union HU4 { _Float16 h[4]; ushort4 u; };
union HU8 { _Float16 h[8]; uint4 u; };
union HU2 { _Float16 h[2]; unsigned u; };

__device__ __forceinline__ void split4(float4 v, HU4& hi, HU4& lo) {
    hi.h[0] = (_Float16)v.x; lo.h[0] = (_Float16)(v.x - (float)hi.h[0]);
    hi.h[1] = (_Float16)v.y; lo.h[1] = (_Float16)(v.y - (float)hi.h[1]);
    hi.h[2] = (_Float16)v.z; lo.h[2] = (_Float16)(v.z - (float)hi.h[2]);
    hi.h[3] = (_Float16)v.w; lo.h[3] = (_Float16)(v.w - (float)hi.h[3]);
}

__device__ __forceinline__ void cast4(float4 v, HU4& hi) {
    hi.h[0] = (_Float16)v.x; hi.h[1] = (_Float16)v.y;
    hi.h[2] = (_Float16)v.z; hi.h[3] = (_Float16)v.w;
}

// ---------------- Kernel 1: mixed-precision MFMA GEMM, fused fp32->fp16 split ----------------
// Y[2048][1664] = x @ [Wq|Wk|Wv|gw1|cw1|pad]^T.
// QKV N-blocks (bn<1536): plain fp16 (proven r5/r6, absmax 0.146).
// Gate N-blocks (bn>=1536): fp16x3 hi/lo -- T_i must be exact.
__global__ __launch_bounds__(256) void k_gemm3(
    const float* __restrict__ X,
    const float* __restrict__ Wq, const float* __restrict__ Wk,
    const float* __restrict__ Wv, const float* __restrict__ gw1,
    const float* __restrict__ cw1,
    float* __restrict__ Y)
{
    __shared__ _Float16 AsH[4][64][8];
    __shared__ _Float16 BsH[4][64][8];
    __shared__ _Float16 AsL[4][64][8];
    __shared__ _Float16 BsL[4][64][8];

    const int bn = blockIdx.x * 64, bm = blockIdx.y * 64;
    const int tid = threadIdx.x, w = tid >> 6, l = tid & 63;
    const int mB = (w & 1) * 32, nB = (w >> 1) * 32;
    const int sr = tid >> 2, sk = tid & 3;
    const int fr = l & 15, fk = l >> 4;
    const bool gate = (bn >= 1536);           // block-uniform

    const float* asrc = X + (bm + sr) * 512;
    const int brow = bn + sr;
    const float* bsrc;
    bool bvalid = true;
    if      (brow < 512)  bsrc = Wq  + brow * 512;
    else if (brow < 1024) bsrc = Wk  + (brow - 512) * 512;
    else if (brow < 1536) bsrc = Wv  + (brow - 1024) * 512;
    else if (brow < 1600) bsrc = gw1 + (brow - 1536) * 512;
    else if (brow < 1632) bsrc = cw1 + (brow - 1600) * 512;
    else { bsrc = Wq; bvalid = false; }

    f32x4 acc[2][2] = {};
    const float4 z4{0.f, 0.f, 0.f, 0.f};

    float4 pa0 = *(const float4*)(asrc + sk * 8);
    float4 pa1 = *(const float4*)(asrc + sk * 8 + 4);
    float4 pb0 = bvalid ? *(const float4*)(bsrc + sk * 8)     : z4;
    float4 pb1 = bvalid ? *(const float4*)(bsrc + sk * 8 + 4) : z4;

    for (int k0 = 0; k0 < 512; k0 += 32) {
        __syncthreads();
        if (gate) {
            HU4 h0, l0, h1, l1;
            split4(pa0, h0, l0); split4(pa1, h1, l1);
            *(ushort4*)&AsH[sk][sr][0] = h0.u; *(ushort4*)&AsH[sk][sr][4] = h1.u;
            *(ushort4*)&AsL[sk][sr][0] = l0.u; *(ushort4*)&AsL[sk][sr][4] = l1.u;
            split4(pb0, h0, l0); split4(pb1, h1, l1);
            *(ushort4*)&BsH[sk][sr][0] = h0.u; *(ushort4*)&BsH[sk][sr][4] = h1.u;
            *(ushort4*)&BsL[sk][sr][0] = l0.u; *(ushort4*)&BsL[sk][sr][4] = l1.u;
        } else {
            HU4 h0, h1;
            cast4(pa0, h0); cast4(pa1, h1);
            *(ushort4*)&AsH[sk][sr][0] = h0.u; *(ushort4*)&AsH[sk][sr][4] = h1.u;
            cast4(pb0, h0); cast4(pb1, h1);
            *(ushort4*)&BsH[sk][sr][0] = h0.u; *(ushort4*)&BsH[sk][sr][4] = h1.u;
        }
        __syncthreads();
        const int kn = (k0 + 32) & 511;   // wraps harmlessly on last iter
        pa0 = *(const float4*)(asrc + kn + sk * 8);
        pa1 = *(const float4*)(asrc + kn + sk * 8 + 4);
        if (bvalid) {
            pb0 = *(const float4*)(bsrc + kn + sk * 8);
            pb1 = *(const float4*)(bsrc + kn + sk * 8 + 4);
        }

        f16x8 ah[2];
#pragma unroll
        for (int mt = 0; mt < 2; mt++)
            ah[mt] = *(const f16x8*)&AsH[fk][mB + mt * 16 + fr][0];
        if (gate) {
            f16x8 al[2];
#pragma unroll
            for (int mt = 0; mt < 2; mt++)
                al[mt] = *(const f16x8*)&AsL[fk][mB + mt * 16 + fr][0];
#pragma unroll
            for (int nt = 0; nt < 2; nt++) {
                f16x8 bh = *(const f16x8*)&BsH[fk][nB + nt * 16 + fr][0];
                f16x8 bl = *(const f16x8*)&BsL[fk][nB + nt * 16 + fr][0];
#pragma unroll
                for (int mt = 0; mt < 2; mt++) {
                    acc[mt][nt] = __builtin_amdgcn_mfma_f32_16x16x32_f16(ah[mt], bh, acc[mt][nt], 0, 0, 0);
                    acc[mt][nt] = __builtin_amdgcn_mfma_f32_16x16x32_f16(ah[mt], bl, acc[mt][nt], 0, 0, 0);
                    acc[mt][nt] = __builtin_amdgcn_mfma_f32_16x16x32_f16(al[mt], bh, acc[mt][nt], 0, 0, 0);
                }
            }
        } else {
#pragma unroll
            for (int nt = 0; nt < 2; nt++) {
                f16x8 bh = *(const f16x8*)&BsH[fk][nB + nt * 16 + fr][0];
#pragma unroll
                for (int mt = 0; mt < 2; mt++)
                    acc[mt][nt] = __builtin_amdgcn_mfma_f32_16x16x32_f16(ah[mt], bh, acc[mt][nt], 0, 0, 0);
            }
        }
    }

#pragma unroll
    for (int mt = 0; mt < 2; mt++) {
#pragma unroll
        for (int nt = 0; nt < 2; nt++) {
            const int j = bn + nB + nt * 16 + fr;
#pragma unroll
            for (int rr = 0; rr < 4; rr++) {
                const int i = bm + mB + mt * 16 + fk * 4 + rr;
                Y[i * 1664 + j] = acc[mt][nt][rr];
            }
        }
    }
}

// ---------------- Kernel 2: LIF + fused gate-layers-2/3 + ballot bit-pack + v_mean transpose ----
// grid (64, 32): blockIdx.y = bh, blockIdx.x = 8-token s-block. 256 thr = 4 waves,
// 2 LIF rounds -> 2048 blocks = 8 blocks/CU (max waves/SIMD) to hide the serial
// dependent sep_mad chain. Gate layers 2/3 recomputed per block (bit-identical).
__global__ __launch_bounds__(256) void k_lif(
    const float* __restrict__ qkvh1,         // [2048][1664]  (q|k|v|h1raw per row)
    const float* __restrict__ gb1, const float* __restrict__ cb1,
    const float* __restrict__ gw2, const float* __restrict__ gb2,
    const float* __restrict__ gw3, const float* __restrict__ gb3,
    const float* __restrict__ cw2, const float* __restrict__ cb2,
    const float* __restrict__ pAlpha, const float* __restrict__ pBeta,
    unsigned long long* __restrict__ qbits,  // [(bh*20)+t]*512 + s
    unsigned long long* __restrict__ kbits,
    _Float16* __restrict__ vmT,              // [bh][d][s]
    int* __restrict__ Ti, float* __restrict__ ti_out)
{
    __shared__ _Float16 cnts[64][10];        // [d][s_local 0..7], pad 10
    __shared__ float h1s[8][100];
    __shared__ float w2s[32][65];            // pad 65: conflict-free
    __shared__ float h2s[8][36];
    __shared__ int tis[8];
    const int tid = threadIdx.x;
    const int wid = tid >> 6, lane = tid & 63;
    const int bh = blockIdx.y, s0 = blockIdx.x * 8;
    const int b = bh >> 3, h = bh & 7;
    const float alpha = pAlpha[0], beta = pBeta[0];

    for (int i = tid; i < 2048; i += 256) w2s[i >> 6][i & 63] = gw2[i];
    for (int i = tid; i < 768; i += 256) {
        const int r = i / 96, c = i % 96;
        const float v = qkvh1[(long)(b * 512 + s0 + r) * 1664 + 1536 + c]
                        + (c < 64 ? gb1[c] : cb1[c - 64]);
        h1s[r][c] = fmaxf(v, 0.f);
    }
    __syncthreads();
    {
        const int tok = tid >> 5, o2 = tid & 31;   // 8 tokens x 32 outs = 256
        float a = gb2[o2];
        for (int k = 0; k < 64; k++) a = fmaf(w2s[o2][k], h1s[tok][k], a);
        h2s[tok][o2] = fmaxf(a, 0.f);
    }
    __syncthreads();
    if (tid < 8) {
        const int tok = tid;
        float gg = gb3[0], cc = cb2[0];
        for (int k = 0; k < 32; k++) {
            gg = fmaf(gw3[k], h2s[tok][k], gg);
            cc = fmaf(cw2[k], h1s[tok][64 + k], cc);
        }
        float g = 1.f / (1.f + expf(-gg));
        float c = 1.f / (1.f + expf(-cc));
        float p1 = 0.7f * g, p2 = 0.3f * c;
        asm volatile("" : "+v"(p1), "+v"(p2));
        float comb = p1 + p2;
        float tf = ceilf(comb * 20.0f);
        tf = fminf(fmaxf(tf, 1.f), 20.f);
        tis[tok] = (int)tf;
        Ti[b * 512 + s0 + tok] = (int)tf;        // redundant x8 across h, identical
        ti_out[b * 512 + s0 + tok] = tf;
    }
    __syncthreads();

    const float* qrow0 = qkvh1 + (long)(b * 512 + s0 + wid) * 1664 + h * 64 + lane;
    float cq = qrow0[0], ck = qrow0[512], cv = qrow0[1024];

    for (int r = 0; r < 2; r++) {
        const int tl = r * 4 + wid;              // token_local 0..7
        const int s = s0 + tl;
        float nq = 0.f, nk = 0.f, nv = 0.f;
        if (r < 1) {
            const float* qr = qkvh1 + (long)(b * 512 + s + 4) * 1664 + h * 64 + lane;
            nq = qr[0]; nk = qr[512]; nv = qr[1024];
        }
        const int T = tis[tl];
        float iq = 0.f, vq = 0.f, ik = 0.f, vk = 0.f, iv = 0.f, vv = 0.f;
        int cnt = 0;
        const int base = (bh * 20) * 512 + s;
#pragma unroll
        for (int t = 0; t < 20; t++) {
            iq = sep_mad(alpha, iq, cq); vq = sep_mad(beta, vq, iq);
            bool sq = vq >= 1.0f; vq = sq ? 0.f : vq;
            ik = sep_mad(alpha, ik, ck); vk = sep_mad(beta, vk, ik);
            bool sk = vk >= 1.0f; vk = sk ? 0.f : vk;
            iv = sep_mad(alpha, iv, cv); vv = sep_mad(beta, vv, iv);
            bool sv = vv >= 1.0f; vv = sv ? 0.f : vv;
            bool act = t < T;
            unsigned long long mq = __ballot(sq && act);
            unsigned long long mk = __ballot(sk && act);
            if (lane == 0) {
                qbits[base + t * 512] = mq;
                kbits[base + t * 512] = mk;
            }
            cnt += (sv && act) ? 1 : 0;
        }
        cnts[lane][tl] = (_Float16)((float)cnt / 20.0f);
        cq = nq; ck = nk; cv = nv;
    }
    __syncthreads();
    // write vmT[bh][d][s0..s0+7]: thread (d = tid>>2, q = tid&3) -> 2 fp16 = 4B
    const int d = tid >> 2, q = tid & 3;
    HU2 o;
    o.h[0] = cnts[d][q * 2];
    o.h[1] = cnts[d][q * 2 + 1];
    *(unsigned*)(vmT + (bh * 64 + d) * 512 + s0 + q * 2) = o.u;
}

// ---------------- Kernel 3: popcount scores + softmax -> attn + fused AV -> hout ----------------
// Block = (bh, 16 q-rows). After softmax the 16x512 attn tile is in LDS (fp16, exact
// conversion identical to old k_av staging) -> each wave MFMAs a 16x16 d-tile of hout.
__global__ __launch_bounds__(256) void k_scores_av(
    const unsigned long long* __restrict__ qbits,
    const unsigned long long* __restrict__ kbits,
    float* __restrict__ attn,
    const int* __restrict__ Ti, float* __restrict__ regp,
    const _Float16* __restrict__ vmT,   // [bh][d][s]
    _Float16* __restrict__ hout)        // [tok][h*64+d] fp16
{
    const int bh = blockIdx.x >> 5;            // 0..31
    const int i0 = (blockIdx.x & 31) * 16;
    const int base = bh * 20 * 512;
    __shared__ unsigned long long qs[20][16];
    __shared__ _Float16 sc16[16][520];         // pad 520: rows 1040B, 16B-aligned
    const int tid = threadIdx.x;
    for (int idx = tid; idx < 320; idx += 256) {
        int t = idx >> 4, r = idx & 15;
        qs[t][r] = qbits[base + t * 512 + i0 + r];
    }
    int Tmax = 0;
    const int tb = (bh >> 3) * 512 + i0;
#pragma unroll
    for (int r = 0; r < 16; r++) Tmax = max(Tmax, Ti[tb + r]);
    __syncthreads();

    {
        const unsigned long long* kbp = kbits + base + 2 * tid;
        int acc0[16] = {}, acc1[16] = {};
        for (int tc = 0; tc < 4; tc++) {
            if (tc * 5 >= Tmax) break;
            unsigned long long kv0[5], kv1[5];
#pragma unroll
            for (int t = 0; t < 5; t++) {
                ulonglong2 kk = *(const ulonglong2*)(kbp + (tc * 5 + t) * 512);
                kv0[t] = kk.x; kv1[t] = kk.y;
            }
#pragma unroll
            for (int r = 0; r < 16; r++) {
#pragma unroll
                for (int t = 0; t < 5; t++) {
                    unsigned long long qv = qs[tc * 5 + t][r];
                    acc0[r] += __popcll(qv & kv0[t]);
                    acc1[r] += __popcll(qv & kv1[t]);
                }
            }
        }
#pragma unroll
        for (int r = 0; r < 16; r++) {
            HU2 p;                              // counts <= 1280: *0.125 exact in fp16
            p.h[0] = (_Float16)((float)acc0[r] * 0.125f);
            p.h[1] = (_Float16)((float)acc1[r] * 0.125f);
            *(unsigned*)&sc16[r][2 * tid] = p.u;
        }
    }
    __syncthreads();

    const int wid = tid >> 6, lane = tid & 63;
#pragma unroll
    for (int rr = 0; rr < 4; rr++) {
        const int r = wid * 4 + rr;
        float vals[8];
        float m = -1e30f;
#pragma unroll
        for (int k = 0; k < 8; k++) { vals[k] = (float)sc16[r][lane + 64 * k]; m = fmaxf(m, vals[k]); }
#pragma unroll
        for (int off = 32; off; off >>= 1) m = fmaxf(m, __shfl_xor(m, off));
        float sum = 0.f;
#pragma unroll
        for (int k = 0; k < 8; k++) { vals[k] = expf(vals[k] - m); sum += vals[k]; }
#pragma unroll
        for (int off = 32; off; off >>= 1) sum += __shfl_xor(sum, off);
        float* arow = attn + ((long)bh * 512 + (i0 + r)) * 512;
#pragma unroll
        for (int k = 0; k < 8; k++) {
            const float o = vals[k] / sum;
            arow[lane + 64 * k] = o;
            sc16[r][lane + 64 * k] = (_Float16)o;   // same conversion old k_av applied
        }
    }

    if (blockIdx.x == 0 && tid < 64) {
        int s = 0;
        for (int k = tid; k < 2048; k += 64) s += Ti[k];
#pragma unroll
        for (int off = 32; off; off >>= 1) s += __shfl_xor(s, off);
        if (tid == 0) regp[0] = 1e-3f * ((float)s / 2048.0f);
    }
    __syncthreads();

    // ---- fused AV: wave wid handles d-tile [wid*16, wid*16+16) ----
    const int fr = lane & 15, fk = lane >> 4;
    const int b = bh >> 3, h = bh & 7;
    f32x4 acc = {};
    const _Float16* bsrc = vmT + (bh * 64 + wid * 16 + fr) * 512;
#pragma unroll
    for (int k0 = 0; k0 < 512; k0 += 32) {
        f16x8 av = *(const f16x8*)&sc16[fr][k0 + fk * 8];
        f16x8 bv = *(const f16x8*)(bsrc + k0 + fk * 8);
        acc = __builtin_amdgcn_mfma_f32_16x16x32_f16(av, bv, acc, 0, 0, 0);
    }
    const int d = wid * 16 + fr;
#pragma unroll
    for (int rr = 0; rr < 4; rr++) {
        const int i = i0 + fk * 4 + rr;
        hout[(b * 512 + i) * 512 + h * 64 + d] = (_Float16)acc[rr];
    }
}

// ---------------- Kernel 4: Wo projection, fused fp32->fp16 weight convert ----------------
// BM=32, BN=64 -> grid (8,64) = 512 blocks (2/CU). Same K-order per output: bit-identical.
__global__ __launch_bounds__(256) void k_gemmWo(
    const _Float16* __restrict__ A, const float* __restrict__ Wo,
    const float* __restrict__ bias, float* __restrict__ Y)
{
    __shared__ _Float16 As[4][32][8];
    __shared__ _Float16 Bs[4][64][8];

    const int bn = blockIdx.x * 64, bm = blockIdx.y * 32;
    const int tid = threadIdx.x, w = tid >> 6, l = tid & 63;
    const int nB = w * 16;                    // wave-tile 32(m) x 16(n)
    const int sr = tid >> 2, sk = tid & 3;    // B staging: 64 rows x 4 kgroups
    const int ar = tid >> 3, ak = tid & 3;    // A staging: threads<256: 32 rows x 4 kgroups (tid&4 unused lanes write dup-free via guard)
    const int fr = l & 15, fk = l >> 4;

    f32x4 acc[2] = {};

    const float* bsrc = Wo + (bn + sr) * 512;
    const bool doA = ((tid & 4) == 0);        // 128 threads stage A (32 rows x 4 kgroups)
    uint4 pA = {};
    if (doA) pA = *(const uint4*)(A + (bm + ar) * 512 + ak * 8);
    float4 pb0 = *(const float4*)(bsrc + sk * 8);
    float4 pb1 = *(const float4*)(bsrc + sk * 8 + 4);

    for (int k0 = 0; k0 < 512; k0 += 32) {
        __syncthreads();
        {
            HU4 h0, h1;
            cast4(pb0, h0); cast4(pb1, h1);
            if (doA) *(uint4*)&As[ak][ar][0] = pA;
            *(ushort4*)&Bs[sk][sr][0] = h0.u; *(ushort4*)&Bs[sk][sr][4] = h1.u;
        }
        __syncthreads();
        const int kn = (k0 + 32) & 511;
        if (doA) pA = *(const uint4*)(A + (bm + ar) * 512 + kn + ak * 8);
        pb0 = *(const float4*)(bsrc + kn + sk * 8);
        pb1 = *(const float4*)(bsrc + kn + sk * 8 + 4);

        f16x8 bh = *(const f16x8*)&Bs[fk][nB + fr][0];
#pragma unroll
        for (int mt = 0; mt < 2; mt++) {
            f16x8 ah = *(const f16x8*)&As[fk][mt * 16 + fr][0];
            acc[mt] = __builtin_amdgcn_mfma_f32_16x16x32_f16(ah, bh, acc[mt], 0, 0, 0);
        }
    }

#pragma unroll
    for (int mt = 0; mt < 2; mt++) {
        const int j = bn + nB + fr;
        const float badd = bias[j];
#pragma unroll
        for (int rr = 0; rr < 4; rr++) {
            const int i = bm + mt * 16 + fk * 4 + rr;
            Y[i * 512 + j] = acc[mt][rr] + badd;
        }
    }
}

extern "C" void kernel_launch(void* const* d_in, const int* in_sizes, int n_in,
                              void* d_out, int out_size, void* d_ws, size_t ws_size,
                              hipStream_t stream)
{
    const float* x    = (const float*)d_in[0];
    const float* Wq   = (const float*)d_in[1];
    const float* Wk   = (const float*)d_in[2];
    const float* Wv   = (const float*)d_in[3];
    const float* Wo   = (const float*)d_in[4];
    const float* bo   = (const float*)d_in[5];
    const float* gw1  = (const float*)d_in[6];
    const float* gb1  = (const float*)d_in[7];
    const float* gw2  = (const float*)d_in[8];
    const float* gb2  = (const float*)d_in[9];
    const float* gw3  = (const float*)d_in[10];
    const float* gb3  = (const float*)d_in[11];
    const float* cw1  = (const float*)d_in[12];
    const float* cb1  = (const float*)d_in[13];
    const float* cw2  = (const float*)d_in[14];
    const float* cb2  = (const float*)d_in[15];
    const float* alpha = (const float*)d_in[16];
    const float* beta  = (const float*)d_in[17];

    float* out   = (float*)d_out;                 // [2048*512]
    float* attn  = out + 1048576;                 // [32][512][512]
    float* regp  = out + 1048576 + 8388608;
    float* tiout = regp + 1;

    // workspace (~23.1 MB, no aliasing):
    char* ws = (char*)d_ws;
    float*    qkvh1  = (float*)ws;                            // [2048][1664] fp32, 13.63 MB
    unsigned long long* qb = (unsigned long long*)(ws + 13631488);   // 2.62 MB
    unsigned long long* kb = (unsigned long long*)(ws + 16252928);   // 2.62 MB
    _Float16* vmT    = (_Float16*)(ws + 18874368);            // 2 MB
    _Float16* hout_h = (_Float16*)(ws + 20971520);            // 2 MB
    int*      Ti     = (int*)(ws + 23068672);                 // 8 KB

    k_gemm3<<<dim3(26, 32), 256, 0, stream>>>(x, Wq, Wk, Wv, gw1, cw1, qkvh1);
    k_lif<<<dim3(64, 32), 256, 0, stream>>>(qkvh1, gb1, cb1, gw2, gb2, gw3, gb3,
                                            cw2, cb2, alpha, beta, qb, kb, vmT, Ti, tiout);
    k_scores_av<<<1024, 256, 0, stream>>>(qb, kb, attn, Ti, regp, vmT, hout_h);
    k_gemmWo<<<dim3(8, 64), 256, 0, stream>>>(hout_h, Wo, bo, out);
}